// Round 13
// baseline (149.809 us; speedup 1.0000x reference)
//
#include <hip/hip_runtime.h>

#define BB 16
#define CC 64
#define ICC 32
#define NN 4096   // F*T
#define MM 1024   // 32*32

typedef __attribute__((ext_vector_type(8))) short short8;
typedef __attribute__((ext_vector_type(4))) float f32x4;

static __device__ __forceinline__ unsigned cvt_pk_bf16(float lo, float hi) {
    unsigned d;
    asm("v_cvt_pk_bf16_f32 %0, %1, %2" : "=v"(d) : "v"(lo), "v"(hi));
    return d;
}
static __device__ __forceinline__ short8 as_s8(uint4 u) {
    union { uint4 a; short8 b; } t; t.a = u; return t.b;
}
static __device__ __forceinline__ float bf16_to_f32(unsigned u) {
    return __uint_as_float(u << 16);
}

// ---- K1: psi/phi conv + 2x2 maxpool (thread-local m-pair) + a_buf + c_buf ----
__global__ void __launch_bounds__(256) k_pool(
        const float* __restrict__ x,
        const float* __restrict__ psi_w, const float* __restrict__ psi_b,
        const float* __restrict__ phi_w, const float* __restrict__ phi_b,
        const float* __restrict__ theta_w, const float* __restrict__ theta_b,
        const float* __restrict__ concat_w,
        unsigned* __restrict__ psi_pk, float* __restrict__ c_buf,
        float* __restrict__ a_buf, float* __restrict__ sumbuf) {
    __shared__ float pw[CC * ICC];   // [c][ic]
    __shared__ float fw[CC * ICC];
    __shared__ float vth[CC];
    __shared__ float xt[CC * 64];    // [c][row2][32]
    __shared__ float sconst;
    int tid = threadIdx.x;
    int b = blockIdx.x >> 6;
    int mtile = blockIdx.x & 63;     // 16 m-values per block
    int fp = mtile >> 1;             // pooled row (same for all 16 m)
    int tpb = (mtile & 1) * 16;      // pooled col base

    // zero this batch's BN-stat slice (one block per b does it, before k_attn runs)
    if (mtile == 0 && tid < 128) sumbuf[b * 128 + tid] = 0.f;

    for (int i = tid; i < CC * ICC; i += 256) {
        int ic = i >> 6, c = i & 63;
        pw[c * ICC + ic] = psi_w[i];
        fw[c * ICC + ic] = phi_w[i];
    }
    if (tid < CC) {
        float s = 0.f;
        for (int ic = 0; ic < ICC; ++ic) s += concat_w[ic] * theta_w[ic * CC + tid];
        vth[tid] = s;
    }
    if (tid == 255) {
        float s = 0.f;
        for (int ic = 0; ic < ICC; ++ic) s += concat_w[ic] * theta_b[ic];
        sconst = s;
    }
    // stage x tile: 64 c x 2 rows x 32 cols
    const float* xb = x + (size_t)b * CC * NN;
    for (int i = tid; i < 1024; i += 256) {
        int c = i >> 4, row = (i >> 3) & 1, jj = i & 7;
        float4 v = *(const float4*)(xb + c * NN + (2 * fp + row) * 64 + 2 * tpb + jj * 4);
        *(float4*)&xt[c * 64 + row * 32 + jj * 4] = v;
    }
    __syncthreads();

    int ic = tid & 31;
    int mp = tid >> 5;               // m-pair index 0..7 -> m0 = mtile*16 + 2*mp
    float p00=0,p01=0,p02=0,p03=0, p10=0,p11=0,p12=0,p13=0;
    float q00=0,q01=0,q02=0,q03=0, q10=0,q11=0,q12=0,q13=0;
    for (int c = 0; c < CC; ++c) {
        float4 r0 = *(const float4*)&xt[c * 64 + mp * 4];        // row 0, cols 4mp..4mp+3
        float4 r1 = *(const float4*)&xt[c * 64 + 32 + mp * 4];   // row 1
        float wp = pw[c * ICC + ic], wf = fw[c * ICC + ic];
        p00 += wp*r0.x; p01 += wp*r0.y; p02 += wp*r1.x; p03 += wp*r1.y;
        p10 += wp*r0.z; p11 += wp*r0.w; p12 += wp*r1.z; p13 += wp*r1.w;
        q00 += wf*r0.x; q01 += wf*r0.y; q02 += wf*r1.x; q03 += wf*r1.y;
        q10 += wf*r0.z; q11 += wf*r0.w; q12 += wf*r1.z; q13 += wf*r1.w;
    }
    float pb = psi_b[ic], fb = phi_b[ic];
    float psi0 = fmaxf(fmaxf(p00,p01),fmaxf(p02,p03)) + pb;
    float psi1 = fmaxf(fmaxf(p10,p11),fmaxf(p12,p13)) + pb;
    float phi0 = fmaxf(fmaxf(q00,q01),fmaxf(q02,q03)) + fb;
    float phi1 = fmaxf(fmaxf(q10,q11),fmaxf(q12,q13)) + fb;

    int m0 = mtile * 16 + 2 * mp;
    float wd0 = concat_w[2 * ICC], wd1 = concat_w[2 * ICC + 1];
    float wph = concat_w[ICC + ic];
    float v0 = wph * phi0, v1 = wph * phi1;
    for (int off = 16; off >= 1; off >>= 1) {
        v0 += __shfl_xor(v0, off, 32);
        v1 += __shfl_xor(v1, off, 32);
    }
    if (ic == 0) {
        int tp = tpb + 2 * mp;
        c_buf[b * MM + m0]     = v0 - (wd0 * (fp * (1.f/31.f)) + wd1 * (tp * (1.f/31.f)));
        c_buf[b * MM + m0 + 1] = v1 - (wd0 * (fp * (1.f/31.f)) + wd1 * ((tp + 1) * (1.f/31.f)));
    }
    // psi bf16 pair, MFMA-B fragment order (thread-local pack, no shfl)
    int mpg = mtile * 8 + mp;                 // global m-pair 0..511
    int ks = mpg >> 4, kg = (mpg >> 2) & 3, cidx = mpg & 3;
    psi_pk[b * 16384 + ks * 512 + (ic >> 4) * 256 + kg * 64 + (ic & 15) * 4 + cidx]
        = cvt_pk_bf16(psi0, psi1);

    // a_buf: 64 pixels per block, threads with ic<8
    if (ic < 8) {
        int pix = mp * 8 + ic;
        int row = pix >> 5, colo = pix & 31;
        float sa = 0.f;
        #pragma unroll 8
        for (int c = 0; c < CC; ++c) sa += vth[c] * xt[c * 64 + row * 32 + colo];
        int f = 2 * fp + row, t = 2 * tpb + colo;
        a_buf[b * NN + f * 64 + t] = sa + sconst + wd0 * (f * (1.f/63.f)) + wd1 * (t * (1.f/63.f));
    }
}

static __device__ __forceinline__ void mfma_step(
        int ks, const float* c_lds, int hi4, float a0, float a1,
        uint4 bu0, uint4 bu1,
        f32x4& acc00, f32x4& acc01, f32x4& acc10, f32x4& acc11) {
    float4 c0 = *(const float4*)&c_lds[ks * 32 + hi4 * 8];
    float4 c1 = *(const float4*)&c_lds[ks * 32 + hi4 * 8 + 4];
    uint4 up;
    up.x = cvt_pk_bf16(fmaxf(a0 + c0.x, 0.f), fmaxf(a0 + c0.y, 0.f));
    up.y = cvt_pk_bf16(fmaxf(a0 + c0.z, 0.f), fmaxf(a0 + c0.w, 0.f));
    up.z = cvt_pk_bf16(fmaxf(a0 + c1.x, 0.f), fmaxf(a0 + c1.y, 0.f));
    up.w = cvt_pk_bf16(fmaxf(a0 + c1.z, 0.f), fmaxf(a0 + c1.w, 0.f));
    short8 ua0 = as_s8(up);
    up.x = cvt_pk_bf16(fmaxf(a1 + c0.x, 0.f), fmaxf(a1 + c0.y, 0.f));
    up.y = cvt_pk_bf16(fmaxf(a1 + c0.z, 0.f), fmaxf(a1 + c0.w, 0.f));
    up.z = cvt_pk_bf16(fmaxf(a1 + c1.x, 0.f), fmaxf(a1 + c1.y, 0.f));
    up.w = cvt_pk_bf16(fmaxf(a1 + c1.z, 0.f), fmaxf(a1 + c1.w, 0.f));
    short8 ua1 = as_s8(up);
    short8 vb0 = as_s8(bu0), vb1 = as_s8(bu1);
    acc00 = __builtin_amdgcn_mfma_f32_16x16x32_bf16(ua0, vb0, acc00, 0, 0, 0);
    acc01 = __builtin_amdgcn_mfma_f32_16x16x32_bf16(ua0, vb1, acc01, 0, 0, 0);
    acc10 = __builtin_amdgcn_mfma_f32_16x16x32_bf16(ua1, vb0, acc10, 0, 0, 0);
    acc11 = __builtin_amdgcn_mfma_f32_16x16x32_bf16(ua1, vb1, acc11, 0, 0, 0);
}

// ---- K2: MFMA attention + output conv -> wy16 (bf16) + fused BN partial sums ----
__global__ void __launch_bounds__(256) k_attn(
        const float* __restrict__ a_buf, const float* __restrict__ c_buf,
        const unsigned* __restrict__ psi_pk,
        const float* __restrict__ W_w, const float* __restrict__ W_b,
        unsigned short* __restrict__ wy16, float* __restrict__ sumbuf) {
    __shared__ float c_lds[MM];          // 4 KB
    __shared__ float W_lds[CC * ICC];    // 8 KB [o][ic]
    __shared__ float Wb_lds[CC];
    __shared__ float yT[ICC * 130];      // transposed y, padded
    int tid = threadIdx.x;
    int b = blockIdx.x >> 5;
    int ntile = blockIdx.x & 31;         // 128 pixels per block
    for (int i = tid; i < MM; i += 256) c_lds[i] = c_buf[b * MM + i];
    for (int i = tid; i < CC * ICC; i += 256) W_lds[i] = W_w[(i >> 5) * (ICC + 1) + (i & 31)];
    if (tid < CC) Wb_lds[tid] = W_b[tid];

    int w = tid >> 6, lane = tid & 63;
    int lo4 = lane & 15, hi4 = lane >> 4;
    const float* ab = a_buf + b * NN + ntile * 128 + w * 32;
    float a0 = ab[lo4], a1 = ab[16 + lo4];

    f32x4 acc00 = {0.f,0.f,0.f,0.f}, acc01 = {0.f,0.f,0.f,0.f};
    f32x4 acc10 = {0.f,0.f,0.f,0.f}, acc11 = {0.f,0.f,0.f,0.f};

    const uint4* pf4 = (const uint4*)psi_pk + (size_t)b * 4096;
    __syncthreads();

    uint4 p0a = pf4[lane],       p0b = pf4[64 + lane];
    uint4 p1a = pf4[128 + lane], p1b = pf4[192 + lane];
    for (int ks = 0; ks < 32; ks += 2) {
        uint4 n0a, n0b, n1a, n1b;
        bool more = (ks + 2 < 32);
        if (more) {
            n0a = pf4[(ks + 2) * 128 + lane]; n0b = pf4[(ks + 2) * 128 + 64 + lane];
            n1a = pf4[(ks + 3) * 128 + lane]; n1b = pf4[(ks + 3) * 128 + 64 + lane];
        }
        mfma_step(ks,     c_lds, hi4, a0, a1, p0a, p0b, acc00, acc01, acc10, acc11);
        mfma_step(ks + 1, c_lds, hi4, a0, a1, p1a, p1b, acc00, acc01, acc10, acc11);
        if (more) { p0a = n0a; p0b = n0b; p1a = n1a; p1b = n1b; }
    }

    const float inv = 1.0f / (float)MM;
    #pragma unroll
    for (int r = 0; r < 4; ++r) {
        yT[lo4 * 130 + w * 32 + hi4 * 4 + r]             = acc00[r] * inv;
        yT[(16 + lo4) * 130 + w * 32 + hi4 * 4 + r]      = acc01[r] * inv;
        yT[lo4 * 130 + w * 32 + 16 + hi4 * 4 + r]        = acc10[r] * inv;
        yT[(16 + lo4) * 130 + w * 32 + 16 + hi4 * 4 + r] = acc11[r] * inv;
    }
    __syncthreads();

    // output conv: 128 pixels x 64 o, thread = (pixel, o-half); store bf16.
    // Each wave covers 64 pixels of ONE o per od -> butterfly gives per-(block,o)
    // BN partials; stats accumulate the bf16-ROUNDED value (self-consistent with k_final).
    int p = tid & 127, oh = tid >> 7;
    float yv[ICC];
    #pragma unroll
    for (int icx = 0; icx < ICC; ++icx) yv[icx] = yT[icx * 130 + p];
    unsigned short* wyp = wy16 + (size_t)b * CC * NN + ntile * 128 + p;
    float* sb = sumbuf + b * 128;
    #pragma unroll 4
    for (int od = 0; od < 32; ++od) {
        int o = oh * 32 + od;
        float s = Wb_lds[o];
        const float* wrow = &W_lds[o * ICC];
        #pragma unroll
        for (int icx = 0; icx < ICC; ++icx) s += wrow[icx] * yv[icx];
        unsigned u = cvt_pk_bf16(s, 0.f) & 0xffffu;
        wyp[(size_t)o * NN] = (unsigned short)u;
        float sf = bf16_to_f32(u);
        float s1 = sf, s2 = sf * sf;
        #pragma unroll
        for (int off = 32; off >= 1; off >>= 1) {
            s1 += __shfl_xor(s1, off, 64);
            s2 += __shfl_xor(s2, off, 64);
        }
        if (lane == 0) {
            atomicAdd(&sb[o], s1);
            atomicAdd(&sb[64 + o], s2);
        }
    }
}

// ---- K3: BN finalize (per-block, o uniform; reduce per-b slices) + normalize + residual ----
__global__ void __launch_bounds__(256) k_final(
        float* __restrict__ out, const float* __restrict__ x,
        const unsigned short* __restrict__ wy16,
        const float* __restrict__ sumbuf,
        const float* __restrict__ bn_gamma, const float* __restrict__ bn_beta) {
    __shared__ float s_sc, s_sh;
    size_t i = (size_t)blockIdx.x * 256 + threadIdx.x;   // float4 index
    int o = (int)((i >> 10) & 63);                       // uniform per block
    if (threadIdx.x == 0) {
        float S = 0.f, S2 = 0.f;
        for (int bb = 0; bb < BB; ++bb) {
            S  += sumbuf[bb * 128 + o];
            S2 += sumbuf[bb * 128 + 64 + o];
        }
        float nN = (float)(BB * NN);
        float mean = S / nN;
        float var = S2 / nN - mean * mean;
        float sc = bn_gamma[o] * rsqrtf(var + 1e-5f);
        s_sc = sc;
        s_sh = bn_beta[o] - mean * sc;
    }
    __syncthreads();
    float sc = s_sc, sh = s_sh;
    uint2 wv = ((const uint2*)wy16)[i];
    float4 x4 = ((const float4*)x)[i];
    float4 r;
    r.x = bf16_to_f32(wv.x & 0xffffu) * sc + sh + x4.x;
    r.y = bf16_to_f32(wv.x >> 16)     * sc + sh + x4.y;
    r.z = bf16_to_f32(wv.y & 0xffffu) * sc + sh + x4.z;
    r.w = bf16_to_f32(wv.y >> 16)     * sc + sh + x4.w;
    ((float4*)out)[i] = r;
}

extern "C" void kernel_launch(void* const* d_in, const int* in_sizes, int n_in,
                              void* d_out, int out_size, void* d_ws, size_t ws_size,
                              hipStream_t stream) {
    const float* x        = (const float*)d_in[0];
    const float* psi_w    = (const float*)d_in[1];
    const float* psi_b    = (const float*)d_in[2];
    const float* theta_w  = (const float*)d_in[3];
    const float* theta_b  = (const float*)d_in[4];
    const float* phi_w    = (const float*)d_in[5];
    const float* phi_b    = (const float*)d_in[6];
    const float* concat_w = (const float*)d_in[7];
    const float* W_w      = (const float*)d_in[8];
    const float* W_b      = (const float*)d_in[9];
    const float* bn_gamma = (const float*)d_in[10];
    const float* bn_beta  = (const float*)d_in[11];

    float* ws = (float*)d_ws;
    float*          a_buf  = ws;                              // 65536 floats
    float*          c_buf  = a_buf + BB * NN;                 // 16384
    unsigned*       psi_pk = (unsigned*)(c_buf + BB * MM);    // 262144 uints
    float*          sumbuf = (float*)(psi_pk + BB * 16384);   // [b][2][64] = 2048 floats
    unsigned short* wy16   = (unsigned short*)(ws + 346112);  // BB*CC*NN ushorts (8.4MB), 16B-aligned
    float*          out    = (float*)d_out;

    k_pool<<<BB * 64, 256, 0, stream>>>(x, psi_w, psi_b, phi_w, phi_b,
                                        theta_w, theta_b, concat_w,
                                        psi_pk, c_buf, a_buf, sumbuf);
    k_attn<<<BB * 32, 256, 0, stream>>>(a_buf, c_buf, psi_pk, W_w, W_b, wy16, sumbuf);
    k_final<<<BB * CC * NN / 1024, 256, 0, stream>>>(out, x, wy16, sumbuf, bn_gamma, bn_beta);
}